// Round 7
// baseline (467.224 us; speedup 1.0000x reference)
//
#include <hip/hip_runtime.h>
#include <stdint.h>

// GPUHausdorffLoss — R16: FULL FUSION. One kernel (2048 blk x 256 thr, all
// co-resident at 4 blk/CU) runs all phases; one hipMemsetAsync zeroes the
// 1.5KB flag region. Rationale: static accounting shows kernel work ~135us
// vs bench 233us — the ~95us residual is launch/drain overhead (R15's K2
// rewrite moved nothing; dispatch-ID spacing shows ~9 dispatches/iter).
//  Phase 1 (all blocks): R15 K1 verbatim (rolled rows, P/Q/R ring, 1-row
//    prefetch, 8-chain interleaved threefry w/ asm alignbit, batched atomic).
//    Then: fence + done_img[side]++ (release).
//  Phase 2 (slice==0 blocks): spin done_img==16, acquire; resolve (256-thr,
//    global 3-pass: fast-path 3-bin coarse select, ballot emission, exact
//    ties; slow full-rescan fallback). Then fence + rdone[img]=1.
//  Phase 3 (slices 8..11 -> 512 virtual haus blocks): spin rdone[iOwn/iOth],
//    acquire; haus partial max -> atomicMax(g_hmax) + ticket; 512th block
//    computes mean (same op order as original fin_kernel).
// Deadlock-free: whole grid co-resident (20KB LDS, <=128 VGPR at bounds
// (256,4)); even under partial residency, phase-1-only blocks exit & drain.

#define HH 512
#define WW 512
#define NPIX (HH * WW)
#define NSEL 1000
#define SLICE_CAP 320
#define CUTM (253u << 14)                     // m-threshold (top 3 of 256 bins)
#define BITCUT ((((253u << 15) - 1u)) << 9)   // bits >= BITCUT  <=>  m >= CUTM
#define ROWS_PER 32

#if __has_builtin(__builtin_amdgcn_alignbit)
__device__ __forceinline__ uint32_t rotl32(uint32_t x, int r) {
  return __builtin_amdgcn_alignbit(x, x, (32 - r) & 31);
}
#else
__device__ __forceinline__ uint32_t rotl32(uint32_t x, int r) {
  return (x << r) | (x >> (32 - r));
}
#endif

// Single-instruction rotate: v_alignbit_b32 d, x, x, (32-R).
template <int R>
__device__ __forceinline__ uint32_t rotlT(uint32_t x) {
  uint32_t d;
  asm("v_alignbit_b32 %0, %1, %1, %2" : "=v"(d) : "v"(x), "n"(32 - R));
  return d;
}

// JAX threefry2x32: 20 rounds, key schedule every 4.
__device__ __forceinline__ void tf2x32(uint32_t k0, uint32_t k1,
                                       uint32_t c0, uint32_t c1,
                                       uint32_t& o0, uint32_t& o1) {
  uint32_t ks2 = k0 ^ k1 ^ 0x1BD11BDAu;
  uint32_t x0 = c0 + k0, x1 = c1 + k1;
#define TF_R(r) { x0 += x1; x1 = rotl32(x1, (r)); x1 ^= x0; }
  TF_R(13) TF_R(15) TF_R(26) TF_R(6)
  x0 += k1;  x1 += ks2 + 1u;
  TF_R(17) TF_R(29) TF_R(16) TF_R(24)
  x0 += ks2; x1 += k0 + 2u;
  TF_R(13) TF_R(15) TF_R(26) TF_R(6)
  x0 += k0;  x1 += k1 + 3u;
  TF_R(17) TF_R(29) TF_R(16) TF_R(24)
  x0 += k1;  x1 += ks2 + 4u;
  TF_R(13) TF_R(15) TF_R(26) TF_R(6)
  x0 += ks2; x1 += k0 + 5u;
#undef TF_R
  o0 = x0; o1 = x1;
}

// Exact rank value of score = 2.0f + uniform(bits): bits(score) - bits(2.0f).
__device__ __forceinline__ uint32_t m_from_bits(uint32_t bits) {
  float noise = __uint_as_float((bits >> 9) | 0x3F800000u) - 1.0f;
  float score = 2.0f + noise;
  return __float_as_uint(score) - 0x40000000u;  // 0 .. 0x400000 inclusive
}

__device__ __forceinline__ uint32_t pixel_m(uint32_t k0, uint32_t k1, int p) {
  uint32_t b1, b2;
  tf2x32(k0, k1, 0u, (uint32_t)p, b1, b2);
  return m_from_bits(b1 ^ b2);
}

__device__ __forceinline__ float sigf(float x) { return 1.0f / (1.0f + __expf(-x)); }

__device__ __forceinline__ float ldval(const float* __restrict__ img, int r, int c, bool isPred) {
  if (r < 0 || r > HH - 1 || c < 0 || c > WW - 1) return 0.0f;  // conv zero-pad (post-sigmoid)
  float v = img[(size_t)r * WW + c];
  return isPred ? sigf(v) : v;
}

__device__ __forceinline__ uint32_t pack_pt(uint32_t p) {
  return ((p >> 9) << 16) | (p & 511u);
}

// ---------------- Phase 1 body (== R15 K1) ----------------
template <bool PRED>
__device__ __forceinline__ void sobel_body(const float* __restrict__ img, int b,
                                           int slice, int t,
                                           unsigned long long* stage, int* s_cn,
                                           int* s_cv) {
  const int lane = t & 63, w = t >> 6;
  const int rbase = slice * ROWS_PER + 8 * w;  // this wave's first compute row
  uint32_t k0, k1;
  tf2x32(0u, 1u, 0u, (uint32_t)b, k0, k1);
  k0 = __builtin_amdgcn_readfirstlane(k0);  // wave-uniform -> pin to SGPR
  k1 = __builtin_amdgcn_readfirstlane(k1);
  const uint32_t ks2 = k0 ^ k1 ^ 0x1BD11BDAu;

  float P[10], Q[10], R[10];  // processed 3-row window (static indices only)
  float4 na, nb;              // raw row in flight (pre-sigmoid, no halos)
  int cnt = 0;
  const uint32_t pbase = (uint32_t)((rbase << 9) + (lane << 3));

  auto issue = [&](int rn) {  // issue-only raw load; no dependent ops
    if ((unsigned)rn < (unsigned)HH) {  // wave-uniform branch
      const float* rp = img + ((size_t)rn << 9) + (lane << 3);
      na = *(const float4*)rp;
      nb = *(const float4*)(rp + 4);
    }
  };
  auto promote = [&](float (&vv)[10], int rn) {  // raw -> processed
    if ((unsigned)rn < (unsigned)HH) {  // wave-uniform branch
      float4 x = na, y = nb;
      if (PRED) {
        x.x = sigf(x.x); x.y = sigf(x.y); x.z = sigf(x.z); x.w = sigf(x.w);
        y.x = sigf(y.x); y.y = sigf(y.y); y.z = sigf(y.z); y.w = sigf(y.w);
      }
      vv[1] = x.x; vv[2] = x.y; vv[3] = x.z; vv[4] = x.w;
      vv[5] = y.x; vv[6] = y.y; vv[7] = y.z; vv[8] = y.w;
      float l = __shfl_up(y.w, 1);
      float r = __shfl_down(x.x, 1);
      vv[0] = (lane == 0) ? 0.0f : l;   // conv zero-pad at col -1
      vv[9] = (lane == 63) ? 0.0f : r;  // conv zero-pad at col 512
    } else {
#pragma unroll
      for (int i = 0; i < 10; ++i) vv[i] = 0.0f;
    }
  };

  // prologue: P = row rbase-1, Q = row rbase; row rbase+1 left in flight
  issue(rbase - 1); promote(P, rbase - 1);
  issue(rbase);     promote(Q, rbase);
  issue(rbase + 1);

#pragma unroll 1
  for (int r = 0; r < 8; ++r) {  // compute row rbase+r — ROLLED
    promote(R, rbase + r + 1);       // consume in-flight raw (loaded 1 body ago)
    if (r < 7) issue(rbase + r + 2); // next raw; reads of na/nb already done
    __builtin_amdgcn_sched_barrier(0);  // pin load issue above the hash block

    const uint32_t prow = pbase + ((uint32_t)r << 9);
    // ---- threefry: 8 interleaved chains; round 1 folded into init ----
    uint32_t X0[8], X1[8];
    const uint32_t pk = prow + k1;
    const uint32_t s0 = pk + k0;  // X0 after round-1 add, minus j
#pragma unroll
    for (int j = 0; j < 8; ++j) {
      uint32_t x1i = pk + (uint32_t)j;
      X0[j] = s0 + (uint32_t)j;              // = k0 + (pk + j)
      X1[j] = rotlT<13>(x1i) ^ X0[j];        // round 1 complete
    }
#define RND(rr)                                                         \
  _Pragma("unroll") for (int j = 0; j < 8; ++j) {                       \
    X0[j] += X1[j];                                                     \
    X1[j] = rotlT<(rr)>(X1[j]) ^ X0[j];                                 \
  }
#define INJ(ka, kb, i)                                                  \
  _Pragma("unroll") for (int j = 0; j < 8; ++j) {                       \
    X0[j] += (ka);                                                      \
    X1[j] += (kb) + (uint32_t)(i);                                      \
  }
    RND(15) RND(26) RND(6)  INJ(k1, ks2, 1)
    RND(17) RND(29) RND(16) RND(24) INJ(ks2, k0, 2)
    RND(13) RND(15) RND(26) RND(6)  INJ(k0, k1, 3)
    RND(17) RND(29) RND(16) RND(24) INJ(k1, ks2, 4)
    RND(13) RND(15) RND(26) RND(6)  INJ(ks2, k0, 5)
#undef RND
#undef INJ
    uint32_t bits[8];
#pragma unroll
    for (int j = 0; j < 8; ++j) bits[j] = X0[j] ^ X1[j];

    // ---- sobel + masks ----
    float da[10], e[10];
#pragma unroll
    for (int k = 0; k < 10; ++k) {
      da[k] = R[k] - P[k];
      e[k] = P[k] + 2.0f * Q[k] + R[k];
    }
    uint32_t candmask = 0;
#pragma unroll
    for (int j = 0; j < 8; ++j) {
      float gx = e[j + 2] - e[j];
      float gy = da[j] + 2.0f * da[j + 1] + da[j + 2];
      bool vld = (gx * gx + gy * gy + 1e-8f) > 0.01f;  // sqrt(x)>0.1 <=> x>0.01
      cnt += vld ? 1 : 0;
      candmask |= ((vld && bits[j] >= BITCUT) ? 1u : 0u) << j;
    }
    if (candmask) {  // rare: ~1.2% of pixels -> ONE atomic, then free stores
      int base = atomicAdd(s_cn, __popc(candmask));
      do {
        int j = __ffs(candmask) - 1;
        candmask &= candmask - 1;
        if (base < SLICE_CAP) {
          uint32_t m = m_from_bits(bits[j]);
          stage[base] = ((unsigned long long)m << 32) | (prow + (uint32_t)j);
        }
        ++base;
      } while (candmask);
    }
#pragma unroll
    for (int k = 0; k < 10; ++k) { P[k] = Q[k]; Q[k] = R[k]; }  // rotate ring
  }
#pragma unroll
  for (int o = 32; o > 0; o >>= 1) cnt += __shfl_down(cnt, o);
  if (lane == 0) atomicAdd(s_cv, cnt);
}

// ---------------- fused kernel ----------------
__global__ __launch_bounds__(256, 4) void fused_kernel(
    const float* __restrict__ pred, const float* __restrict__ tgt,
    int2* __restrict__ g_scnt, unsigned long long* __restrict__ g_cand,
    uint32_t* __restrict__ g_pts, int* __restrict__ g_counts,
    int* __restrict__ done_img, int* __restrict__ rdone,
    uint32_t* __restrict__ g_hmax, int* __restrict__ g_done,
    float* __restrict__ out) {
  const int bid = blockIdx.x;
  const int side = bid >> 4, slice = bid & 15;
  const int t = threadIdx.x;
  const int lane = t & 63;

  __shared__ unsigned long long stage[SLICE_CAP];  // 2.5 KB (phase 1)
  __shared__ int s_cn, s_cv;
  __shared__ int segc[16], s_scx[16], s_scy[16];   // resolve
  __shared__ int s_info[4];
  __shared__ int ch[256], fh[1024], aux[256];
  __shared__ unsigned long long ties[256];
  __shared__ int s_pos, s_nt, s_T1, s_r1, s_T2, s_r2;
  __shared__ float2 opts[NSEL];                    // haus (8 KB)
  __shared__ float red[256];
  __shared__ int s_tk;
  // total ~20 KB -> 4 blocks/CU -> whole 2048-block grid co-resident

  // ================= phase 1: sobel + candidates =================
  if (t == 0) { s_cn = 0; s_cv = 0; }
  __syncthreads();
  if (side < 64)
    sobel_body<true>(pred + (size_t)side * NPIX, side, slice, t, stage, &s_cn, &s_cv);
  else
    sobel_body<false>(tgt + (size_t)(side - 64) * NPIX, side, slice, t, stage, &s_cn, &s_cv);
  __syncthreads();
  {
    const int raw = s_cn;
    const int n = raw < SLICE_CAP ? raw : SLICE_CAP;
    for (int i = t; i < n; i += 256) g_cand[(size_t)bid * SLICE_CAP + i] = stage[i];
    if (t == 0) g_scnt[bid] = make_int2(s_cv, raw);
  }
  __syncthreads();                     // drains all this block's global stores
  if (t == 0) { __threadfence(); atomicAdd(&done_img[side], 1); }  // release

  // ================= phase 2: resolve (slice-0 blocks) =================
  if (slice == 0) {
    const int img = side;
    if (t == 0) {
      while (atomicAdd(&done_img[img], 0) < 16) __builtin_amdgcn_s_sleep(8);
      __threadfence();                 // acquire
    }
    __syncthreads();

    if (t < 16) {
      int2 v = g_scnt[img * 16 + t];
      s_scx[t] = v.x; s_scy[t] = v.y;
      segc[t] = v.y < SLICE_CAP ? v.y : SLICE_CAP;
    }
    if (t == 0) { s_pos = 0; s_nt = 0; }
    __syncthreads();
    if (t == 0) {
      int cv = 0, hi = 0, ovf = 0;
      for (int s = 0; s < 16; ++s) {
        cv += s_scx[s]; hi += s_scy[s];
        if (s_scy[s] > SLICE_CAP) ovf = 1;
      }
      s_info[0] = cv; s_info[1] = hi; s_info[2] = ovf;
    }
    __syncthreads();
    const int cv = s_info[0];
    if (cv == 0) {  // center fallback
      if (t == 0) { g_pts[img * NSEL] = (256u << 16) | 256u; g_counts[img] = 1; }
    } else {
      const int need = cv < NSEL ? cv : NSEL;
      const bool slow = (s_info[2] != 0) || (s_info[1] < need);
      unsigned long long* C = g_cand + (size_t)img * 16 * SLICE_CAP;

      if (slow) {
        // ---- exact rebuild (statistically never): rescan whole image ----
        const bool isPred = img < 64;
        const float* im = isPred ? pred + (size_t)img * NPIX
                                 : tgt + (size_t)(img - 64) * NPIX;
        uint32_t k0, k1;
        tf2x32(0u, 1u, 0u, (uint32_t)img, k0, k1);
        ch[t] = 0;
        __syncthreads();
        for (int p = t; p < NPIX; p += 256) {
          int r = p >> 9, c = p & 511;
          float gx = (ldval(im, r - 1, c + 1, isPred) - ldval(im, r - 1, c - 1, isPred)) +
                     2.0f * (ldval(im, r, c + 1, isPred) - ldval(im, r, c - 1, isPred)) +
                     (ldval(im, r + 1, c + 1, isPred) - ldval(im, r + 1, c - 1, isPred));
          float gy = (ldval(im, r + 1, c - 1, isPred) - ldval(im, r - 1, c - 1, isPred)) +
                     2.0f * (ldval(im, r + 1, c, isPred) - ldval(im, r - 1, c, isPred)) +
                     (ldval(im, r + 1, c + 1, isPred) - ldval(im, r - 1, c + 1, isPred));
          if ((gx * gx + gy * gy + 1e-8f) > 0.01f) {
            uint32_t m = pixel_m(k0, k1, p);
            uint32_t cb = m >> 14; if (cb > 255u) cb = 255u;
            atomicAdd(&ch[cb], 1);
          }
        }
        __syncthreads();
        {
          aux[t] = ch[t];
          __syncthreads();
          for (int o = 1; o < 256; o <<= 1) {
            int v = (t + o < 256) ? aux[t + o] : 0;
            __syncthreads();
            aux[t] += v;
            __syncthreads();
          }
          int nx = (t + 1 < 256) ? aux[t + 1] : 0;
          if (aux[t] >= need && nx < need) s_T1 = t;
          __syncthreads();
        }
        const uint32_t Tc = (uint32_t)s_T1;
        if (t == 0) s_info[3] = 0;
        __syncthreads();
        for (int p = t; p < NPIX; p += 256) {
          int r = p >> 9, c = p & 511;
          float gx = (ldval(im, r - 1, c + 1, isPred) - ldval(im, r - 1, c - 1, isPred)) +
                     2.0f * (ldval(im, r, c + 1, isPred) - ldval(im, r, c - 1, isPred)) +
                     (ldval(im, r + 1, c + 1, isPred) - ldval(im, r + 1, c - 1, isPred));
          float gy = (ldval(im, r + 1, c - 1, isPred) - ldval(im, r - 1, c - 1, isPred)) +
                     2.0f * (ldval(im, r + 1, c, isPred) - ldval(im, r - 1, c, isPred)) +
                     (ldval(im, r + 1, c + 1, isPred) - ldval(im, r - 1, c + 1, isPred));
          if ((gx * gx + gy * gy + 1e-8f) > 0.01f) {
            uint32_t m = pixel_m(k0, k1, p);
            uint32_t cb = m >> 14; if (cb > 255u) cb = 255u;
            if (cb >= Tc) {
              int i = atomicAdd(&s_info[3], 1);
              if (i < 16 * SLICE_CAP) C[i] = ((unsigned long long)m << 32) | (uint32_t)p;
            }
          }
        }
        __syncthreads();
        if (t == 0) {
          int nc = s_info[3] < 16 * SLICE_CAP ? s_info[3] : 16 * SLICE_CAP;
          segc[0] = nc;
          for (int s = 1; s < 16; ++s) segc[s] = 0;
        }
        __syncthreads();
      }

      // ---- coarse select ----
      ch[t] = 0;
      for (int i = t; i < 1024; i += 256) fh[i] = 0;
      __syncthreads();
      if (!slow) {
        // fast path: cb guaranteed in {253,254,255} (BITCUT) -> 3 local
        // counters + wave reduce (3 atomics/wave, not 1/candidate)
        int l0 = 0, l1 = 0, l2 = 0;
        for (int s = 0; s < 16; ++s) {
          const unsigned long long* sp = C + (size_t)s * SLICE_CAP;
          for (int i = t; i < segc[s]; i += 256) {
            uint32_t cb = (uint32_t)(sp[i] >> 32) >> 14;
            if (cb >= 255u) ++l2; else if (cb == 254u) ++l1; else ++l0;
          }
        }
#pragma unroll
        for (int o = 32; o > 0; o >>= 1) {
          l0 += __shfl_down(l0, o); l1 += __shfl_down(l1, o); l2 += __shfl_down(l2, o);
        }
        if (lane == 0) {
          if (l0) atomicAdd(&ch[253], l0);
          if (l1) atomicAdd(&ch[254], l1);
          if (l2) atomicAdd(&ch[255], l2);
        }
        __syncthreads();
        if (t == 0) {  // suffix over the 3 known bins (== generic 256 scan)
          int s5 = ch[255], s4 = ch[254] + s5;
          if (s5 >= need)      { s_T1 = 255; s_r1 = need; }
          else if (s4 >= need) { s_T1 = 254; s_r1 = need - s5; }
          else                 { s_T1 = 253; s_r1 = need - s4; }
        }
        __syncthreads();
      } else {
        for (int s = 0; s < 16; ++s) {
          const unsigned long long* sp = C + (size_t)s * SLICE_CAP;
          for (int i = t; i < segc[s]; i += 256) {
            uint32_t cb = (uint32_t)(sp[i] >> 32) >> 14; if (cb > 255u) cb = 255u;
            atomicAdd(&ch[cb], 1);
          }
        }
        __syncthreads();
        aux[t] = ch[t];
        __syncthreads();
        for (int o = 1; o < 256; o <<= 1) {
          int v = (t + o < 256) ? aux[t + o] : 0;
          __syncthreads();
          aux[t] += v;
          __syncthreads();
        }
        int nx = (t + 1 < 256) ? aux[t + 1] : 0;
        if (aux[t] >= need && nx < need) { s_T1 = t; s_r1 = need - nx; }
        __syncthreads();
      }
      const uint32_t T1 = (uint32_t)s_T1;
      const int r1 = s_r1;
      const uint32_t baseM = T1 << 14;

      // ---- pass 2: emit cb>T1 (ballot-aggregated), fine-hist cb==T1 ----
      for (int s = 0; s < 16; ++s) {
        const unsigned long long* sp = C + (size_t)s * SLICE_CAP;
        const int sn = segc[s];
        for (int i0 = 0; i0 < sn; i0 += 256) {
          const int i = i0 + t;
          const bool in = i < sn;
          unsigned long long e = in ? sp[i] : 0ull;
          uint32_t m = (uint32_t)(e >> 32), p = (uint32_t)e;
          uint32_t cb = m >> 14; if (cb > 255u) cb = 255u;
          bool emit = in && cb > T1;
          unsigned long long msk = __ballot(emit);
          if (msk) {
            int leader = __ffsll((unsigned long long)msk) - 1;
            int bpos = 0;
            if (lane == leader) bpos = atomicAdd(&s_pos, __popcll(msk));
            bpos = __shfl(bpos, leader);
            if (emit)
              g_pts[img * NSEL + bpos + __popcll(msk & ((1ull << lane) - 1ull))] = pack_pt(p);
          }
          if (in && cb == T1) {
            uint32_t f = (m - baseM) >> 4; if (f > 1023u) f = 1023u;
            atomicAdd(&fh[f], 1);
          }
        }
      }
      __syncthreads();
      // fine suffix scan: 4 bins/thread + 256-wide scan
      {
        int base4 = 4 * t, sv = 0;
        for (int j = 3; j >= 0; --j) { sv += fh[base4 + j]; fh[base4 + j] = sv; }
        aux[t] = sv;
        __syncthreads();
        for (int o = 1; o < 256; o <<= 1) {
          int v = (t + o < 256) ? aux[t + o] : 0;
          __syncthreads();
          aux[t] += v;
          __syncthreads();
        }
        int add = (t < 255) ? aux[t + 1] : 0;
        for (int j = 0; j < 4; ++j) fh[base4 + j] += add;
        __syncthreads();
        for (int j = 0; j < 4; ++j) {
          int idx = base4 + j;
          int sfx = fh[idx];
          int nx2 = (idx < 1023) ? fh[idx + 1] : 0;
          if (sfx >= r1 && nx2 < r1) { s_T2 = idx; s_r2 = r1 - nx2; }
        }
        __syncthreads();
      }
      const int T2 = s_T2, r2 = s_r2;

      // ---- pass 3: emit f>T2 (ballot), collect ties f==T2 ----
      for (int s = 0; s < 16; ++s) {
        const unsigned long long* sp = C + (size_t)s * SLICE_CAP;
        const int sn = segc[s];
        for (int i0 = 0; i0 < sn; i0 += 256) {
          const int i = i0 + t;
          const bool in = i < sn;
          unsigned long long e = in ? sp[i] : 0ull;
          uint32_t m = (uint32_t)(e >> 32), p = (uint32_t)e;
          uint32_t cb = m >> 14; if (cb > 255u) cb = 255u;
          uint32_t f = (m - baseM) >> 4; if (f > 1023u) f = 1023u;
          const bool isT1 = in && cb == T1;
          bool emit = isT1 && (int)f > T2;
          bool tie  = isT1 && (int)f == T2;
          unsigned long long msk = __ballot(emit);
          if (msk) {
            int leader = __ffsll((unsigned long long)msk) - 1;
            int bpos = 0;
            if (lane == leader) bpos = atomicAdd(&s_pos, __popcll(msk));
            bpos = __shfl(bpos, leader);
            if (emit)
              g_pts[img * NSEL + bpos + __popcll(msk & ((1ull << lane) - 1ull))] = pack_pt(p);
          }
          unsigned long long mt = __ballot(tie);
          if (mt) {
            int leader = __ffsll((unsigned long long)mt) - 1;
            int bpos = 0;
            if (lane == leader) bpos = atomicAdd(&s_nt, __popcll(mt));
            bpos = __shfl(bpos, leader);
            int idx = bpos + __popcll(mt & ((1ull << lane) - 1ull));
            if (tie && idx < 256) ties[idx] = e;
          }
        }
      }
      __syncthreads();
      const int nt = s_nt < 256 ? s_nt : 256;
      for (int i = t; i < nt; i += 256) {
        unsigned long long e = ties[i];
        uint32_t mi = (uint32_t)(e >> 32), pi = (uint32_t)e;
        int rank = 0;
        for (int j = 0; j < nt; ++j) {
          unsigned long long e2 = ties[j];
          uint32_t mj = (uint32_t)(e2 >> 32), pj = (uint32_t)e2;
          rank += (mj > mi) || (mj == mi && pj < pi);
        }
        if (rank < r2) {
          int pos = atomicAdd(&s_pos, 1);
          g_pts[img * NSEL + pos] = pack_pt(pi);
        }
      }
      __syncthreads();
      if (t == 0) g_counts[img] = s_pos;  // == need
    }
    __syncthreads();                     // drain g_pts/g_counts stores
    if (t == 0) { __threadfence(); atomicExch(&rdone[img], 1); }  // release
  }

  // ================= phase 3: haus (slices 8..11) =================
  if (slice >= 8 && slice < 12) {
    const int h = side * 4 + (slice - 8);  // 0..511 unique
    const int img = h >> 3;
    const int dir = (h >> 2) & 1;
    const int seg = h & 3;
    const int iOwn = dir ? 64 + img : img;
    const int iOth = dir ? img : 64 + img;
    if (t == 0) {
      while (atomicAdd(&rdone[iOwn], 0) == 0) __builtin_amdgcn_s_sleep(8);
      while (atomicAdd(&rdone[iOth], 0) == 0) __builtin_amdgcn_s_sleep(8);
      __threadfence();                   // acquire
    }
    __syncthreads();
    const int nOwn = g_counts[iOwn];
    const int nOth = g_counts[iOth];
    for (int i = t; i < nOth; i += 256) {
      uint32_t v = g_pts[iOth * NSEL + i];
      opts[i] = make_float2((float)(v >> 16), (float)(v & 0xFFFFu));
    }
    __syncthreads();
    float best = 0.0f;
    const int lo = seg * 250;
    const int hi = min(nOwn, lo + 250);
    for (int i = lo + t; i < hi; i += 256) {
      uint32_t v = g_pts[iOwn * NSEL + i];
      float pr = (float)(v >> 16), pc = (float)(v & 0xFFFFu);
      float mn0 = 3.4e38f, mn1 = 3.4e38f, mn2 = 3.4e38f, mn3 = 3.4e38f;
      int j = 0;
      for (; j + 3 < nOth; j += 4) {
        float dr0 = pr - opts[j].x,     dc0 = pc - opts[j].y;
        float dr1 = pr - opts[j + 1].x, dc1 = pc - opts[j + 1].y;
        float dr2 = pr - opts[j + 2].x, dc2 = pc - opts[j + 2].y;
        float dr3 = pr - opts[j + 3].x, dc3 = pc - opts[j + 3].y;
        mn0 = fminf(mn0, dr0 * dr0 + dc0 * dc0);
        mn1 = fminf(mn1, dr1 * dr1 + dc1 * dc1);
        mn2 = fminf(mn2, dr2 * dr2 + dc2 * dc2);
        mn3 = fminf(mn3, dr3 * dr3 + dc3 * dc3);
      }
      for (; j < nOth; ++j) {
        float dr = pr - opts[j].x, dc = pc - opts[j].y;
        mn0 = fminf(mn0, dr * dr + dc * dc);
      }
      float mn = fminf(fminf(mn0, mn1), fminf(mn2, mn3));
      best = fmaxf(best, mn);
    }
    red[t] = best;
    __syncthreads();
    for (int st = 128; st > 0; st >>= 1) {
      if (t < st) red[t] = fmaxf(red[t], red[t + st]);
      __syncthreads();
    }
    // per-img atomic max (d2>=0 so uint order == float order) + ticket;
    // 512th arrival computes the mean (same op order as old fin_kernel).
    if (t == 0) {
      atomicMax(&g_hmax[img], __float_as_uint(red[0]));
      __threadfence();
      s_tk = atomicAdd(g_done, 1);
    }
    __syncthreads();
    if (s_tk == 511) {
      __threadfence();
      if (t < 64) {  // wave 0: lane t owns image t
        uint32_t u = atomicMax(&g_hmax[t], 0u);  // device-scope atomic read
        float diag = sqrtf((float)(HH * HH + WW * WW));
        float hd = sqrtf(fmaxf(__uint_as_float(u), 0.0f)) / diag;
        hd = fminf(fmaxf(hd, 0.0f), 0.1f);
        float s = hd;
        for (int o2 = 32; o2 > 0; o2 >>= 1) s += __shfl_down(s, o2);
        if (t == 0) out[0] = s * 0.015625f;
      }
    }
  }
}

// ---------------- workspace layout (bytes) ----------------
// flags region (done_img[128] | rdone[128] | g_hmax[64] | g_done) zeroed by
// a single hipMemsetAsync each launch; nothing else pre-zeroed.
#define WS_SCNT   0u                          // 2048*8 = 16384
#define WS_COUNTS 16384u                      // 512
#define WS_FLAGS  16896u                      // 1536 (memset region)
#define WS_DONEIMG (WS_FLAGS)                 // 128*4 = 512
#define WS_RDONE  (WS_FLAGS + 512u)           // 128*4 = 512
#define WS_HMAX   (WS_FLAGS + 1024u)          // 64*4 = 256
#define WS_DONE   (WS_FLAGS + 1280u)          // 4
#define WS_PTS    (WS_FLAGS + 1536u)          // 512000
#define WS_CAND   (WS_PTS + 512000u)          // 2048*320*8 = 5242880 (~5.8 MB)

extern "C" void kernel_launch(void* const* d_in, const int* in_sizes, int n_in,
                              void* d_out, int out_size, void* d_ws, size_t ws_size,
                              hipStream_t stream) {
  const float* pred = (const float*)d_in[0];
  const float* tgt = (const float*)d_in[1];
  float* out = (float*)d_out;
  char* ws = (char*)d_ws;
  int2* g_scnt = (int2*)(ws + WS_SCNT);
  int* g_counts = (int*)(ws + WS_COUNTS);
  int* done_img = (int*)(ws + WS_DONEIMG);
  int* rdone = (int*)(ws + WS_RDONE);
  uint32_t* g_hmax = (uint32_t*)(ws + WS_HMAX);
  int* g_done = (int*)(ws + WS_DONE);
  uint32_t* g_pts = (uint32_t*)(ws + WS_PTS);
  unsigned long long* g_cand = (unsigned long long*)(ws + WS_CAND);

  hipMemsetAsync(ws + WS_FLAGS, 0, 1536, stream);
  fused_kernel<<<2048, 256, 0, stream>>>(pred, tgt, g_scnt, g_cand, g_pts,
                                         g_counts, done_img, rdone, g_hmax,
                                         g_done, out);
}

// Round 8
// 258.533 us; speedup vs baseline: 1.8072x; 1.8072x over previous
//
#include <hip/hip_runtime.h>
#include <stdint.h>

// GPUHausdorffLoss — R17: R15 base (best verified 233us) + two shavers.
//  Lesson from R16: bench-total minus dispatch-time is a FIXED ~88us harness
//  residual (restore memsets) regardless of launch count — only kernel time
//  counts. R16's fused kernel convoyed (2048 blks needed 8/CU, bounds gave 4).
//  K1: R15 structure verbatim, plus v_add3_u32 fusion of key-injection adds
//      into the following round's add (4 of 5 injections; -4 VALU/px).
//      Block 0 zeroes rdone/g_hmax/g_done for the post kernel.
//  post_kernel (640 blk x 256): blocks 0-127 resolve image-side bid (R16's
//      verified 256-thread resolve: 3-bin fast coarse select, ballot emission,
//      exact ties, slow full-rescan fallback) then release rdone[img];
//      blocks 128-639 haus (spin rdone[iOwn/iOth], acquire; float4 LDS point
//      reads; 4 accumulators) + ticket finisher (512th computes mean).
//      640 blks @ ~17.5KB LDS -> fully co-resident; resolve never waits ->
//      acyclic dependency, no convoy.

#define HH 512
#define WW 512
#define NPIX (HH * WW)
#define NSEL 1000
#define SLICE_CAP 320
#define CUTM (253u << 14)                     // m-threshold (top 3 of 256 bins)
#define BITCUT ((((253u << 15) - 1u)) << 9)   // bits >= BITCUT  <=>  m >= CUTM
#define ROWS_PER 32

#if __has_builtin(__builtin_amdgcn_alignbit)
__device__ __forceinline__ uint32_t rotl32(uint32_t x, int r) {
  return __builtin_amdgcn_alignbit(x, x, (32 - r) & 31);
}
#else
__device__ __forceinline__ uint32_t rotl32(uint32_t x, int r) {
  return (x << r) | (x >> (32 - r));
}
#endif

// Single-instruction rotate: v_alignbit_b32 d, x, x, (32-R).
template <int R>
__device__ __forceinline__ uint32_t rotlT(uint32_t x) {
  uint32_t d;
  asm("v_alignbit_b32 %0, %1, %1, %2" : "=v"(d) : "v"(x), "n"(32 - R));
  return d;
}

// 2 adds in 1 inst: d = a + b + c (b wave-uniform SGPR; 1 SGPR read is legal).
__device__ __forceinline__ uint32_t add3s(uint32_t a, uint32_t b, uint32_t c) {
  uint32_t d;
  asm("v_add3_u32 %0, %1, %2, %3" : "=v"(d) : "v"(a), "s"(b), "v"(c));
  return d;
}

// JAX threefry2x32: 20 rounds, key schedule every 4.
__device__ __forceinline__ void tf2x32(uint32_t k0, uint32_t k1,
                                       uint32_t c0, uint32_t c1,
                                       uint32_t& o0, uint32_t& o1) {
  uint32_t ks2 = k0 ^ k1 ^ 0x1BD11BDAu;
  uint32_t x0 = c0 + k0, x1 = c1 + k1;
#define TF_R(r) { x0 += x1; x1 = rotl32(x1, (r)); x1 ^= x0; }
  TF_R(13) TF_R(15) TF_R(26) TF_R(6)
  x0 += k1;  x1 += ks2 + 1u;
  TF_R(17) TF_R(29) TF_R(16) TF_R(24)
  x0 += ks2; x1 += k0 + 2u;
  TF_R(13) TF_R(15) TF_R(26) TF_R(6)
  x0 += k0;  x1 += k1 + 3u;
  TF_R(17) TF_R(29) TF_R(16) TF_R(24)
  x0 += k1;  x1 += ks2 + 4u;
  TF_R(13) TF_R(15) TF_R(26) TF_R(6)
  x0 += ks2; x1 += k0 + 5u;
#undef TF_R
  o0 = x0; o1 = x1;
}

// Exact rank value of score = 2.0f + uniform(bits): bits(score) - bits(2.0f).
__device__ __forceinline__ uint32_t m_from_bits(uint32_t bits) {
  float noise = __uint_as_float((bits >> 9) | 0x3F800000u) - 1.0f;
  float score = 2.0f + noise;
  return __float_as_uint(score) - 0x40000000u;  // 0 .. 0x400000 inclusive
}

__device__ __forceinline__ uint32_t pixel_m(uint32_t k0, uint32_t k1, int p) {
  uint32_t b1, b2;
  tf2x32(k0, k1, 0u, (uint32_t)p, b1, b2);
  return m_from_bits(b1 ^ b2);
}

__device__ __forceinline__ float sigf(float x) { return 1.0f / (1.0f + __expf(-x)); }

__device__ __forceinline__ float ldval(const float* __restrict__ img, int r, int c, bool isPred) {
  if (r < 0 || r > HH - 1 || c < 0 || c > WW - 1) return 0.0f;  // conv zero-pad (post-sigmoid)
  float v = img[(size_t)r * WW + c];
  return isPred ? sigf(v) : v;
}

__device__ __forceinline__ uint32_t pack_pt(uint32_t p) {
  return ((p >> 9) << 16) | (p & 511u);
}

// ---------------- K1 ----------------
// Wave spans a full 512-col row: lane owns cols [8*lane, 8*lane+8); v[0]/v[9]
// halos via in-wave shuffles. Rolled row loop; named P/Q/R ring (static
// indices). One raw row in flight, promoted one iteration later.
template <bool PRED>
__device__ __forceinline__ void sobel_body(const float* __restrict__ img, int b,
                                           int slice, int t,
                                           unsigned long long* stage, int* s_cn,
                                           int* s_cv) {
  const int lane = t & 63, w = t >> 6;
  const int rbase = slice * ROWS_PER + 8 * w;  // this wave's first compute row
  uint32_t k0, k1;
  tf2x32(0u, 1u, 0u, (uint32_t)b, k0, k1);
  k0 = __builtin_amdgcn_readfirstlane(k0);  // wave-uniform -> pin to SGPR
  k1 = __builtin_amdgcn_readfirstlane(k1);
  const uint32_t ks2 = k0 ^ k1 ^ 0x1BD11BDAu;
  // injection constants (wave-uniform SGPRs)
  const uint32_t c1_ = ks2 + 1u, c2_ = k0 + 2u, c3_ = k1 + 3u,
                 c4_ = ks2 + 4u, c5_ = k0 + 5u;

  float P[10], Q[10], R[10];  // processed 3-row window (static indices only)
  float4 na, nb;              // raw row in flight (pre-sigmoid, no halos)
  int cnt = 0;
  const uint32_t pbase = (uint32_t)((rbase << 9) + (lane << 3));

  auto issue = [&](int rn) {  // issue-only raw load; no dependent ops
    if ((unsigned)rn < (unsigned)HH) {  // wave-uniform branch
      const float* rp = img + ((size_t)rn << 9) + (lane << 3);
      na = *(const float4*)rp;
      nb = *(const float4*)(rp + 4);
    }
  };
  auto promote = [&](float (&vv)[10], int rn) {  // raw -> processed
    if ((unsigned)rn < (unsigned)HH) {  // wave-uniform branch
      float4 x = na, y = nb;
      if (PRED) {
        x.x = sigf(x.x); x.y = sigf(x.y); x.z = sigf(x.z); x.w = sigf(x.w);
        y.x = sigf(y.x); y.y = sigf(y.y); y.z = sigf(y.z); y.w = sigf(y.w);
      }
      vv[1] = x.x; vv[2] = x.y; vv[3] = x.z; vv[4] = x.w;
      vv[5] = y.x; vv[6] = y.y; vv[7] = y.z; vv[8] = y.w;
      float l = __shfl_up(y.w, 1);
      float r = __shfl_down(x.x, 1);
      vv[0] = (lane == 0) ? 0.0f : l;   // conv zero-pad at col -1
      vv[9] = (lane == 63) ? 0.0f : r;  // conv zero-pad at col 512
    } else {
#pragma unroll
      for (int i = 0; i < 10; ++i) vv[i] = 0.0f;
    }
  };

  // prologue: P = row rbase-1, Q = row rbase; row rbase+1 left in flight
  issue(rbase - 1); promote(P, rbase - 1);
  issue(rbase);     promote(Q, rbase);
  issue(rbase + 1);

#pragma unroll 1
  for (int r = 0; r < 8; ++r) {  // compute row rbase+r — ROLLED
    promote(R, rbase + r + 1);       // consume in-flight raw (loaded 1 body ago)
    if (r < 7) issue(rbase + r + 2); // next raw; reads of na/nb already done
    __builtin_amdgcn_sched_barrier(0);  // pin load issue above the hash block

    const uint32_t prow = pbase + ((uint32_t)r << 9);
    // ---- threefry: 8 interleaved chains; round 1 folded into init;
    //      injections 1-4 fused into the following round via v_add3 ----
    uint32_t X0[8], X1[8];
    const uint32_t pk = prow + k1;
    const uint32_t s0 = pk + k0;  // X0 after round-1 add, minus j
#pragma unroll
    for (int j = 0; j < 8; ++j) {
      uint32_t x1i = pk + (uint32_t)j;
      X0[j] = s0 + (uint32_t)j;              // = k0 + (pk + j)
      X1[j] = rotlT<13>(x1i) ^ X0[j];        // round 1 complete
    }
#define RND(rr)                                                         \
  _Pragma("unroll") for (int j = 0; j < 8; ++j) {                       \
    X0[j] += X1[j];                                                     \
    X1[j] = rotlT<(rr)>(X1[j]) ^ X0[j];                                 \
  }
// fused: {X0+=ka; X1+=kbi} followed by round rr — 4 insts instead of 5
#define FRND(rr, ka, kbi)                                               \
  _Pragma("unroll") for (int j = 0; j < 8; ++j) {                       \
    X1[j] += (kbi);                                                     \
    X0[j] = add3s(X0[j], (ka), X1[j]);                                  \
    X1[j] = rotlT<(rr)>(X1[j]) ^ X0[j];                                 \
  }
    RND(15) RND(26) RND(6)
    FRND(17, k1, c1_)  RND(29) RND(16) RND(24)
    FRND(13, ks2, c2_) RND(15) RND(26) RND(6)
    FRND(17, k0, c3_)  RND(29) RND(16) RND(24)
    FRND(13, k1, c4_)  RND(15) RND(26) RND(6)
#undef RND
#undef FRND
    uint32_t bits[8];
#pragma unroll
    for (int j = 0; j < 8; ++j) bits[j] = (X0[j] + ks2) ^ (X1[j] + c5_);

    // ---- sobel + masks ----
    float da[10], e[10];
#pragma unroll
    for (int k = 0; k < 10; ++k) {
      da[k] = R[k] - P[k];
      e[k] = P[k] + 2.0f * Q[k] + R[k];
    }
    uint32_t candmask = 0;
#pragma unroll
    for (int j = 0; j < 8; ++j) {
      float gx = e[j + 2] - e[j];
      float gy = da[j] + 2.0f * da[j + 1] + da[j + 2];
      bool vld = (gx * gx + gy * gy + 1e-8f) > 0.01f;  // sqrt(x)>0.1 <=> x>0.01
      cnt += vld ? 1 : 0;
      candmask |= ((vld && bits[j] >= BITCUT) ? 1u : 0u) << j;
    }
    if (candmask) {  // rare: ~1.2% of pixels -> ONE atomic, then free stores
      int base = atomicAdd(s_cn, __popc(candmask));
      do {
        int j = __ffs(candmask) - 1;
        candmask &= candmask - 1;
        if (base < SLICE_CAP) {
          uint32_t m = m_from_bits(bits[j]);
          stage[base] = ((unsigned long long)m << 32) | (prow + (uint32_t)j);
        }
        ++base;
      } while (candmask);
    }
#pragma unroll
    for (int k = 0; k < 10; ++k) { P[k] = Q[k]; Q[k] = R[k]; }  // rotate ring
  }
#pragma unroll
  for (int o = 32; o > 0; o >>= 1) cnt += __shfl_down(cnt, o);
  if (lane == 0) atomicAdd(s_cv, cnt);
}

__global__ __launch_bounds__(256, 4) void sobel_cand(
    const float* __restrict__ pred, const float* __restrict__ tgt,
    int2* __restrict__ g_scnt, unsigned long long* __restrict__ g_cand,
    int* __restrict__ rdone, uint32_t* __restrict__ g_hmax,
    int* __restrict__ g_done) {
  const int bid = blockIdx.x;
  const int b = bid >> 4, s = bid & 15;
  const int t = threadIdx.x;
  __shared__ unsigned long long stage[SLICE_CAP];
  __shared__ int s_cn, s_cv;
  if (t == 0) { s_cn = 0; s_cv = 0; }
  if (bid == 0) {  // zero post_kernel's sync state (post launches after K1)
    if (t < 128) rdone[t] = 0;
    else if (t < 192) g_hmax[t - 128] = 0u;
    else if (t == 192) *g_done = 0;
  }
  __syncthreads();
  if (b < 64) sobel_body<true>(pred + (size_t)b * NPIX, b, s, t, stage, &s_cn, &s_cv);
  else        sobel_body<false>(tgt + (size_t)(b - 64) * NPIX, b, s, t, stage, &s_cn, &s_cv);
  __syncthreads();
  const int raw = s_cn;
  const int n = raw < SLICE_CAP ? raw : SLICE_CAP;
  for (int i = t; i < n; i += 256) g_cand[(size_t)bid * SLICE_CAP + i] = stage[i];
  if (t == 0) g_scnt[bid] = make_int2(s_cv, raw);
}

// ---------------- post kernel: resolve (blk 0-127) + haus (blk 128-639) ----
__global__ __launch_bounds__(256) void post_kernel(
    const float* __restrict__ pred, const float* __restrict__ tgt,
    const int2* __restrict__ g_scnt, unsigned long long* __restrict__ g_cand,
    uint32_t* __restrict__ g_pts, int* __restrict__ g_counts,
    int* __restrict__ rdone, uint32_t* __restrict__ g_hmax,
    int* __restrict__ g_done, float* __restrict__ out) {
  const int bid = blockIdx.x;
  const int t = threadIdx.x;
  const int lane = t & 63;

  __shared__ int segc[16], s_scx[16], s_scy[16], s_info[4];
  __shared__ int ch[256], fh[1024], aux[256];
  __shared__ unsigned long long ties[256];
  __shared__ int s_pos, s_nt, s_T1, s_r1, s_T2, s_r2;
  __shared__ __align__(16) float2 opts[NSEL];
  __shared__ float red[256];
  __shared__ int s_tk;
  // ~17.5 KB -> 640 blocks fully co-resident; resolve blocks never wait.

  if (bid < 128) {
    // ================= resolve image-side bid =================
    const int img = bid;
    if (t < 16) {
      int2 v = g_scnt[img * 16 + t];
      s_scx[t] = v.x; s_scy[t] = v.y;
      segc[t] = v.y < SLICE_CAP ? v.y : SLICE_CAP;
    }
    if (t == 0) { s_pos = 0; s_nt = 0; }
    __syncthreads();
    if (t == 0) {
      int cv = 0, hi = 0, ovf = 0;
      for (int s = 0; s < 16; ++s) {
        cv += s_scx[s]; hi += s_scy[s];
        if (s_scy[s] > SLICE_CAP) ovf = 1;
      }
      s_info[0] = cv; s_info[1] = hi; s_info[2] = ovf;
    }
    __syncthreads();
    const int cv = s_info[0];
    if (cv == 0) {  // center fallback
      if (t == 0) { g_pts[img * NSEL] = (256u << 16) | 256u; g_counts[img] = 1; }
    } else {
      const int need = cv < NSEL ? cv : NSEL;
      const bool slow = (s_info[2] != 0) || (s_info[1] < need);
      unsigned long long* C = g_cand + (size_t)img * 16 * SLICE_CAP;

      if (slow) {
        // ---- exact rebuild (statistically never): rescan whole image ----
        const bool isPred = img < 64;
        const float* im = isPred ? pred + (size_t)img * NPIX
                                 : tgt + (size_t)(img - 64) * NPIX;
        uint32_t k0, k1;
        tf2x32(0u, 1u, 0u, (uint32_t)img, k0, k1);
        ch[t] = 0;
        __syncthreads();
        for (int p = t; p < NPIX; p += 256) {
          int r = p >> 9, c = p & 511;
          float gx = (ldval(im, r - 1, c + 1, isPred) - ldval(im, r - 1, c - 1, isPred)) +
                     2.0f * (ldval(im, r, c + 1, isPred) - ldval(im, r, c - 1, isPred)) +
                     (ldval(im, r + 1, c + 1, isPred) - ldval(im, r + 1, c - 1, isPred));
          float gy = (ldval(im, r + 1, c - 1, isPred) - ldval(im, r - 1, c - 1, isPred)) +
                     2.0f * (ldval(im, r + 1, c, isPred) - ldval(im, r - 1, c, isPred)) +
                     (ldval(im, r + 1, c + 1, isPred) - ldval(im, r - 1, c + 1, isPred));
          if ((gx * gx + gy * gy + 1e-8f) > 0.01f) {
            uint32_t m = pixel_m(k0, k1, p);
            uint32_t cb = m >> 14; if (cb > 255u) cb = 255u;
            atomicAdd(&ch[cb], 1);
          }
        }
        __syncthreads();
        {
          aux[t] = ch[t];
          __syncthreads();
          for (int o = 1; o < 256; o <<= 1) {
            int v = (t + o < 256) ? aux[t + o] : 0;
            __syncthreads();
            aux[t] += v;
            __syncthreads();
          }
          int nx = (t + 1 < 256) ? aux[t + 1] : 0;
          if (aux[t] >= need && nx < need) s_T1 = t;
          __syncthreads();
        }
        const uint32_t Tc = (uint32_t)s_T1;
        if (t == 0) s_info[3] = 0;
        __syncthreads();
        for (int p = t; p < NPIX; p += 256) {
          int r = p >> 9, c = p & 511;
          float gx = (ldval(im, r - 1, c + 1, isPred) - ldval(im, r - 1, c - 1, isPred)) +
                     2.0f * (ldval(im, r, c + 1, isPred) - ldval(im, r, c - 1, isPred)) +
                     (ldval(im, r + 1, c + 1, isPred) - ldval(im, r + 1, c - 1, isPred));
          float gy = (ldval(im, r + 1, c - 1, isPred) - ldval(im, r - 1, c - 1, isPred)) +
                     2.0f * (ldval(im, r + 1, c, isPred) - ldval(im, r - 1, c, isPred)) +
                     (ldval(im, r + 1, c + 1, isPred) - ldval(im, r - 1, c + 1, isPred));
          if ((gx * gx + gy * gy + 1e-8f) > 0.01f) {
            uint32_t m = pixel_m(k0, k1, p);
            uint32_t cb = m >> 14; if (cb > 255u) cb = 255u;
            if (cb >= Tc) {
              int i = atomicAdd(&s_info[3], 1);
              if (i < 16 * SLICE_CAP) C[i] = ((unsigned long long)m << 32) | (uint32_t)p;
            }
          }
        }
        __syncthreads();
        if (t == 0) {
          int nc = s_info[3] < 16 * SLICE_CAP ? s_info[3] : 16 * SLICE_CAP;
          segc[0] = nc;
          for (int s = 1; s < 16; ++s) segc[s] = 0;
        }
        __syncthreads();
      }

      // ---- coarse select ----
      ch[t] = 0;
      for (int i = t; i < 1024; i += 256) fh[i] = 0;
      __syncthreads();
      if (!slow) {
        // fast path: cb guaranteed in {253,254,255} (BITCUT) -> 3 local
        // counters + wave reduce (3 atomics/wave, not 1/candidate)
        int l0 = 0, l1 = 0, l2 = 0;
        for (int s = 0; s < 16; ++s) {
          const unsigned long long* sp = C + (size_t)s * SLICE_CAP;
          for (int i = t; i < segc[s]; i += 256) {
            uint32_t cb = (uint32_t)(sp[i] >> 32) >> 14;
            if (cb >= 255u) ++l2; else if (cb == 254u) ++l1; else ++l0;
          }
        }
#pragma unroll
        for (int o = 32; o > 0; o >>= 1) {
          l0 += __shfl_down(l0, o); l1 += __shfl_down(l1, o); l2 += __shfl_down(l2, o);
        }
        if (lane == 0) {
          if (l0) atomicAdd(&ch[253], l0);
          if (l1) atomicAdd(&ch[254], l1);
          if (l2) atomicAdd(&ch[255], l2);
        }
        __syncthreads();
        if (t == 0) {  // suffix over the 3 known bins (== generic 256 scan)
          int s5 = ch[255], s4 = ch[254] + s5;
          if (s5 >= need)      { s_T1 = 255; s_r1 = need; }
          else if (s4 >= need) { s_T1 = 254; s_r1 = need - s5; }
          else                 { s_T1 = 253; s_r1 = need - s4; }
        }
        __syncthreads();
      } else {
        for (int s = 0; s < 16; ++s) {
          const unsigned long long* sp = C + (size_t)s * SLICE_CAP;
          for (int i = t; i < segc[s]; i += 256) {
            uint32_t cb = (uint32_t)(sp[i] >> 32) >> 14; if (cb > 255u) cb = 255u;
            atomicAdd(&ch[cb], 1);
          }
        }
        __syncthreads();
        aux[t] = ch[t];
        __syncthreads();
        for (int o = 1; o < 256; o <<= 1) {
          int v = (t + o < 256) ? aux[t + o] : 0;
          __syncthreads();
          aux[t] += v;
          __syncthreads();
        }
        int nx = (t + 1 < 256) ? aux[t + 1] : 0;
        if (aux[t] >= need && nx < need) { s_T1 = t; s_r1 = need - nx; }
        __syncthreads();
      }
      const uint32_t T1 = (uint32_t)s_T1;
      const int r1 = s_r1;
      const uint32_t baseM = T1 << 14;

      // ---- pass 2: emit cb>T1 (ballot-aggregated), fine-hist cb==T1 ----
      for (int s = 0; s < 16; ++s) {
        const unsigned long long* sp = C + (size_t)s * SLICE_CAP;
        const int sn = segc[s];
        for (int i0 = 0; i0 < sn; i0 += 256) {
          const int i = i0 + t;
          const bool in = i < sn;
          unsigned long long e = in ? sp[i] : 0ull;
          uint32_t m = (uint32_t)(e >> 32), p = (uint32_t)e;
          uint32_t cb = m >> 14; if (cb > 255u) cb = 255u;
          bool emit = in && cb > T1;
          unsigned long long msk = __ballot(emit);
          if (msk) {
            int leader = __ffsll((unsigned long long)msk) - 1;
            int bpos = 0;
            if (lane == leader) bpos = atomicAdd(&s_pos, __popcll(msk));
            bpos = __shfl(bpos, leader);
            if (emit)
              g_pts[img * NSEL + bpos + __popcll(msk & ((1ull << lane) - 1ull))] = pack_pt(p);
          }
          if (in && cb == T1) {
            uint32_t f = (m - baseM) >> 4; if (f > 1023u) f = 1023u;
            atomicAdd(&fh[f], 1);
          }
        }
      }
      __syncthreads();
      // fine suffix scan: 4 bins/thread + 256-wide scan
      {
        int base4 = 4 * t, sv = 0;
        for (int j = 3; j >= 0; --j) { sv += fh[base4 + j]; fh[base4 + j] = sv; }
        aux[t] = sv;
        __syncthreads();
        for (int o = 1; o < 256; o <<= 1) {
          int v = (t + o < 256) ? aux[t + o] : 0;
          __syncthreads();
          aux[t] += v;
          __syncthreads();
        }
        int add = (t < 255) ? aux[t + 1] : 0;
        for (int j = 0; j < 4; ++j) fh[base4 + j] += add;
        __syncthreads();
        for (int j = 0; j < 4; ++j) {
          int idx = base4 + j;
          int sfx = fh[idx];
          int nx2 = (idx < 1023) ? fh[idx + 1] : 0;
          if (sfx >= r1 && nx2 < r1) { s_T2 = idx; s_r2 = r1 - nx2; }
        }
        __syncthreads();
      }
      const int T2 = s_T2, r2 = s_r2;

      // ---- pass 3: emit f>T2 (ballot), collect ties f==T2 ----
      for (int s = 0; s < 16; ++s) {
        const unsigned long long* sp = C + (size_t)s * SLICE_CAP;
        const int sn = segc[s];
        for (int i0 = 0; i0 < sn; i0 += 256) {
          const int i = i0 + t;
          const bool in = i < sn;
          unsigned long long e = in ? sp[i] : 0ull;
          uint32_t m = (uint32_t)(e >> 32), p = (uint32_t)e;
          uint32_t cb = m >> 14; if (cb > 255u) cb = 255u;
          uint32_t f = (m - baseM) >> 4; if (f > 1023u) f = 1023u;
          const bool isT1 = in && cb == T1;
          bool emit = isT1 && (int)f > T2;
          bool tie  = isT1 && (int)f == T2;
          unsigned long long msk = __ballot(emit);
          if (msk) {
            int leader = __ffsll((unsigned long long)msk) - 1;
            int bpos = 0;
            if (lane == leader) bpos = atomicAdd(&s_pos, __popcll(msk));
            bpos = __shfl(bpos, leader);
            if (emit)
              g_pts[img * NSEL + bpos + __popcll(msk & ((1ull << lane) - 1ull))] = pack_pt(p);
          }
          unsigned long long mt = __ballot(tie);
          if (mt) {
            int leader = __ffsll((unsigned long long)mt) - 1;
            int bpos = 0;
            if (lane == leader) bpos = atomicAdd(&s_nt, __popcll(mt));
            bpos = __shfl(bpos, leader);
            int idx = bpos + __popcll(mt & ((1ull << lane) - 1ull));
            if (tie && idx < 256) ties[idx] = e;
          }
        }
      }
      __syncthreads();
      const int nt = s_nt < 256 ? s_nt : 256;
      for (int i = t; i < nt; i += 256) {
        unsigned long long e = ties[i];
        uint32_t mi = (uint32_t)(e >> 32), pi = (uint32_t)e;
        int rank = 0;
        for (int j = 0; j < nt; ++j) {
          unsigned long long e2 = ties[j];
          uint32_t mj = (uint32_t)(e2 >> 32), pj = (uint32_t)e2;
          rank += (mj > mi) || (mj == mi && pj < pi);
        }
        if (rank < r2) {
          int pos = atomicAdd(&s_pos, 1);
          g_pts[img * NSEL + pos] = pack_pt(pi);
        }
      }
      __syncthreads();
      if (t == 0) g_counts[img] = s_pos;  // == need
    }
    __syncthreads();                     // drain g_pts/g_counts stores
    if (t == 0) { __threadfence(); atomicExch(&rdone[img], 1); }  // release

  } else {
    // ================= haus =================
    const int h = bid - 128;             // 0..511
    const int img = h >> 3;
    const int dir = (h >> 2) & 1;
    const int seg = h & 3;
    const int iOwn = dir ? 64 + img : img;
    const int iOth = dir ? img : 64 + img;
    if (t == 0) {
      while (atomicAdd(&rdone[iOwn], 0) == 0) __builtin_amdgcn_s_sleep(8);
      while (atomicAdd(&rdone[iOth], 0) == 0) __builtin_amdgcn_s_sleep(8);
      __threadfence();                   // acquire
    }
    __syncthreads();
    const int nOwn = g_counts[iOwn];
    const int nOth = g_counts[iOth];
    for (int i = t; i < nOth; i += 256) {
      uint32_t v = g_pts[iOth * NSEL + i];
      opts[i] = make_float2((float)(v >> 16), (float)(v & 0xFFFFu));
    }
    __syncthreads();
    const float4* o4 = (const float4*)opts;  // 2 points per read
    float best = 0.0f;
    const int lo = seg * 250;
    const int hi = min(nOwn, lo + 250);
    for (int i = lo + t; i < hi; i += 256) {
      uint32_t v = g_pts[iOwn * NSEL + i];
      float pr = (float)(v >> 16), pc = (float)(v & 0xFFFFu);
      float mn0 = 3.4e38f, mn1 = 3.4e38f, mn2 = 3.4e38f, mn3 = 3.4e38f;
      int j = 0;
      for (; j + 3 < nOth; j += 4) {
        float4 A = o4[j >> 1];        // pts j, j+1
        float4 B = o4[(j >> 1) + 1];  // pts j+2, j+3
        float dr0 = pr - A.x, dc0 = pc - A.y;
        float dr1 = pr - A.z, dc1 = pc - A.w;
        float dr2 = pr - B.x, dc2 = pc - B.y;
        float dr3 = pr - B.z, dc3 = pc - B.w;
        mn0 = fminf(mn0, dr0 * dr0 + dc0 * dc0);
        mn1 = fminf(mn1, dr1 * dr1 + dc1 * dc1);
        mn2 = fminf(mn2, dr2 * dr2 + dc2 * dc2);
        mn3 = fminf(mn3, dr3 * dr3 + dc3 * dc3);
      }
      for (; j < nOth; ++j) {
        float dr = pr - opts[j].x, dc = pc - opts[j].y;
        mn0 = fminf(mn0, dr * dr + dc * dc);
      }
      float mn = fminf(fminf(mn0, mn1), fminf(mn2, mn3));
      best = fmaxf(best, mn);
    }
    red[t] = best;
    __syncthreads();
    for (int st = 128; st > 0; st >>= 1) {
      if (t < st) red[t] = fmaxf(red[t], red[t + st]);
      __syncthreads();
    }
    // per-img atomic max (d2>=0 so uint order == float order) + ticket;
    // 512th arrival computes the mean (same op order as original fin_kernel).
    if (t == 0) {
      atomicMax(&g_hmax[img], __float_as_uint(red[0]));
      __threadfence();
      s_tk = atomicAdd(g_done, 1);
    }
    __syncthreads();
    if (s_tk == 511) {
      __threadfence();
      if (t < 64) {  // wave 0: lane t owns image t
        uint32_t u = atomicMax(&g_hmax[t], 0u);  // device-scope atomic read
        float diag = sqrtf((float)(HH * HH + WW * WW));
        float hd = sqrtf(fmaxf(__uint_as_float(u), 0.0f)) / diag;
        hd = fminf(fmaxf(hd, 0.0f), 0.1f);
        float s = hd;
        for (int o2 = 32; o2 > 0; o2 >>= 1) s += __shfl_down(s, o2);
        if (t == 0) out[0] = s * 0.015625f;
      }
    }
  }
}

// ---------------- workspace layout (bytes) — nothing pre-zeroed ----------
#define WS_SCNT   0u                          // 2048*8 = 16384
#define WS_COUNTS 16384u                      // 512
#define WS_RDONE  16896u                      // 128*4 = 512 (zeroed by K1 blk0)
#define WS_HMAX   (WS_RDONE + 512u)           // 64*4 = 256  (zeroed by K1 blk0)
#define WS_DONE   (WS_HMAX + 256u)            // 4           (zeroed by K1 blk0)
#define WS_PTS    (WS_HMAX + 1024u)           // 512000
#define WS_CAND   (WS_PTS + 512000u)          // 2048*320*8 = 5242880 (~5.8 MB)

extern "C" void kernel_launch(void* const* d_in, const int* in_sizes, int n_in,
                              void* d_out, int out_size, void* d_ws, size_t ws_size,
                              hipStream_t stream) {
  const float* pred = (const float*)d_in[0];
  const float* tgt = (const float*)d_in[1];
  float* out = (float*)d_out;
  char* ws = (char*)d_ws;
  int2* g_scnt = (int2*)(ws + WS_SCNT);
  int* g_counts = (int*)(ws + WS_COUNTS);
  int* rdone = (int*)(ws + WS_RDONE);
  uint32_t* g_hmax = (uint32_t*)(ws + WS_HMAX);
  int* g_done = (int*)(ws + WS_DONE);
  uint32_t* g_pts = (uint32_t*)(ws + WS_PTS);
  unsigned long long* g_cand = (unsigned long long*)(ws + WS_CAND);

  sobel_cand<<<2048, 256, 0, stream>>>(pred, tgt, g_scnt, g_cand, rdone, g_hmax, g_done);
  post_kernel<<<640, 256, 0, stream>>>(pred, tgt, g_scnt, g_cand, g_pts,
                                       g_counts, rdone, g_hmax, g_done, out);
}

// Round 9
// 232.480 us; speedup vs baseline: 2.0097x; 1.1121x over previous
//
#include <hip/hip_runtime.h>
#include <stdint.h>

// GPUHausdorffLoss — R18: REVERT to R15 (best verified 233.4us) + one local
// tweak kept from R17 (haus LDS reads as float4). Lessons closed this round:
//  - R16 full fusion: convoy (grid needed 8 blk/CU, bounds gave 4) -> 378us.
//  - R17 back-end merge: spin-waiting haus blocks contend with resolve ->
//    +25us. The back-end ~40us is NOT removable by launch fusion.
//  - K1 is VALU-issue-bound at ~87% busy across 6 schedule variants; hash
//    (threefry, bit-exact) is irreducible. K1 floor ~103us.
//  - Fixed harness residual ~88us (bench minus dispatch, measured 2 ways).
// Structure: K1 sobel_cand (2048x256, bounds(256,4)); K2 resolve (128x1024,
// LDS-staged, 3-bin fast coarse select, ballot emission, exact ties); K3
// haus (512x256, float4 point reads, 4 accumulators) + fused K4 ticket
// finisher. K1 block 0 zeroes g_hmax/g_done.

#define HH 512
#define WW 512
#define NPIX (HH * WW)
#define NSEL 1000
#define SLICE_CAP 320
#define CUTM (253u << 14)                     // m-threshold (top 3 of 256 bins)
#define BITCUT ((((253u << 15) - 1u)) << 9)   // bits >= BITCUT  <=>  m >= CUTM
#define ROWS_PER 32
#define K2_BS 1024

#if __has_builtin(__builtin_amdgcn_alignbit)
__device__ __forceinline__ uint32_t rotl32(uint32_t x, int r) {
  return __builtin_amdgcn_alignbit(x, x, (32 - r) & 31);
}
#else
__device__ __forceinline__ uint32_t rotl32(uint32_t x, int r) {
  return (x << r) | (x >> (32 - r));
}
#endif

// Single-instruction rotate: v_alignbit_b32 d, x, x, (32-R).
template <int R>
__device__ __forceinline__ uint32_t rotlT(uint32_t x) {
  uint32_t d;
  asm("v_alignbit_b32 %0, %1, %1, %2" : "=v"(d) : "v"(x), "n"(32 - R));
  return d;
}

// JAX threefry2x32: 20 rounds, key schedule every 4.
__device__ __forceinline__ void tf2x32(uint32_t k0, uint32_t k1,
                                       uint32_t c0, uint32_t c1,
                                       uint32_t& o0, uint32_t& o1) {
  uint32_t ks2 = k0 ^ k1 ^ 0x1BD11BDAu;
  uint32_t x0 = c0 + k0, x1 = c1 + k1;
#define TF_R(r) { x0 += x1; x1 = rotl32(x1, (r)); x1 ^= x0; }
  TF_R(13) TF_R(15) TF_R(26) TF_R(6)
  x0 += k1;  x1 += ks2 + 1u;
  TF_R(17) TF_R(29) TF_R(16) TF_R(24)
  x0 += ks2; x1 += k0 + 2u;
  TF_R(13) TF_R(15) TF_R(26) TF_R(6)
  x0 += k0;  x1 += k1 + 3u;
  TF_R(17) TF_R(29) TF_R(16) TF_R(24)
  x0 += k1;  x1 += ks2 + 4u;
  TF_R(13) TF_R(15) TF_R(26) TF_R(6)
  x0 += ks2; x1 += k0 + 5u;
#undef TF_R
  o0 = x0; o1 = x1;
}

// Exact rank value of score = 2.0f + uniform(bits): bits(score) - bits(2.0f).
__device__ __forceinline__ uint32_t m_from_bits(uint32_t bits) {
  float noise = __uint_as_float((bits >> 9) | 0x3F800000u) - 1.0f;
  float score = 2.0f + noise;
  return __float_as_uint(score) - 0x40000000u;  // 0 .. 0x400000 inclusive
}

__device__ __forceinline__ uint32_t pixel_m(uint32_t k0, uint32_t k1, int p) {
  uint32_t b1, b2;
  tf2x32(k0, k1, 0u, (uint32_t)p, b1, b2);
  return m_from_bits(b1 ^ b2);
}

__device__ __forceinline__ float sigf(float x) { return 1.0f / (1.0f + __expf(-x)); }

__device__ __forceinline__ float ldval(const float* __restrict__ img, int r, int c, bool isPred) {
  if (r < 0 || r > HH - 1 || c < 0 || c > WW - 1) return 0.0f;  // conv zero-pad (post-sigmoid)
  float v = img[(size_t)r * WW + c];
  return isPred ? sigf(v) : v;
}

__device__ __forceinline__ uint32_t pack_pt(uint32_t p) {
  return ((p >> 9) << 16) | (p & 511u);
}

// ---------------- K1 ----------------
// Wave spans a full 512-col row: lane owns cols [8*lane, 8*lane+8); v[0]/v[9]
// halos via in-wave shuffles. Rolled row loop; named P/Q/R ring (static
// indices). One raw row in flight, promoted one iteration later.
template <bool PRED>
__device__ __forceinline__ void sobel_body(const float* __restrict__ img, int b,
                                           int slice, int t,
                                           unsigned long long* stage, int* s_cn,
                                           int* s_cv) {
  const int lane = t & 63, w = t >> 6;
  const int rbase = slice * ROWS_PER + 8 * w;  // this wave's first compute row
  uint32_t k0, k1;
  tf2x32(0u, 1u, 0u, (uint32_t)b, k0, k1);
  k0 = __builtin_amdgcn_readfirstlane(k0);  // wave-uniform -> pin to SGPR
  k1 = __builtin_amdgcn_readfirstlane(k1);
  const uint32_t ks2 = k0 ^ k1 ^ 0x1BD11BDAu;

  float P[10], Q[10], R[10];  // processed 3-row window (static indices only)
  float4 na, nb;              // raw row in flight (pre-sigmoid, no halos)
  int cnt = 0;
  const uint32_t pbase = (uint32_t)((rbase << 9) + (lane << 3));

  auto issue = [&](int rn) {  // issue-only raw load; no dependent ops
    if ((unsigned)rn < (unsigned)HH) {  // wave-uniform branch
      const float* rp = img + ((size_t)rn << 9) + (lane << 3);
      na = *(const float4*)rp;
      nb = *(const float4*)(rp + 4);
    }
  };
  auto promote = [&](float (&vv)[10], int rn) {  // raw -> processed
    if ((unsigned)rn < (unsigned)HH) {  // wave-uniform branch
      float4 x = na, y = nb;
      if (PRED) {
        x.x = sigf(x.x); x.y = sigf(x.y); x.z = sigf(x.z); x.w = sigf(x.w);
        y.x = sigf(y.x); y.y = sigf(y.y); y.z = sigf(y.z); y.w = sigf(y.w);
      }
      vv[1] = x.x; vv[2] = x.y; vv[3] = x.z; vv[4] = x.w;
      vv[5] = y.x; vv[6] = y.y; vv[7] = y.z; vv[8] = y.w;
      float l = __shfl_up(y.w, 1);
      float r = __shfl_down(x.x, 1);
      vv[0] = (lane == 0) ? 0.0f : l;   // conv zero-pad at col -1
      vv[9] = (lane == 63) ? 0.0f : r;  // conv zero-pad at col 512
    } else {
#pragma unroll
      for (int i = 0; i < 10; ++i) vv[i] = 0.0f;
    }
  };

  // prologue: P = row rbase-1, Q = row rbase; row rbase+1 left in flight
  issue(rbase - 1); promote(P, rbase - 1);
  issue(rbase);     promote(Q, rbase);
  issue(rbase + 1);

#pragma unroll 1
  for (int r = 0; r < 8; ++r) {  // compute row rbase+r — ROLLED
    promote(R, rbase + r + 1);       // consume in-flight raw (loaded 1 body ago)
    if (r < 7) issue(rbase + r + 2); // next raw; reads of na/nb already done
    __builtin_amdgcn_sched_barrier(0);  // pin load issue above the hash block

    const uint32_t prow = pbase + ((uint32_t)r << 9);
    // ---- threefry: 8 interleaved chains; round 1 folded into init ----
    uint32_t X0[8], X1[8];
    const uint32_t pk = prow + k1;
    const uint32_t s0 = pk + k0;  // X0 after round-1 add, minus j
#pragma unroll
    for (int j = 0; j < 8; ++j) {
      uint32_t x1i = pk + (uint32_t)j;
      X0[j] = s0 + (uint32_t)j;              // = k0 + (pk + j)
      X1[j] = rotlT<13>(x1i) ^ X0[j];        // round 1 complete
    }
#define RND(rr)                                                         \
  _Pragma("unroll") for (int j = 0; j < 8; ++j) {                       \
    X0[j] += X1[j];                                                     \
    X1[j] = rotlT<(rr)>(X1[j]) ^ X0[j];                                 \
  }
#define INJ(ka, kb, i)                                                  \
  _Pragma("unroll") for (int j = 0; j < 8; ++j) {                       \
    X0[j] += (ka);                                                      \
    X1[j] += (kb) + (uint32_t)(i);                                      \
  }
    RND(15) RND(26) RND(6)  INJ(k1, ks2, 1)
    RND(17) RND(29) RND(16) RND(24) INJ(ks2, k0, 2)
    RND(13) RND(15) RND(26) RND(6)  INJ(k0, k1, 3)
    RND(17) RND(29) RND(16) RND(24) INJ(k1, ks2, 4)
    RND(13) RND(15) RND(26) RND(6)  INJ(ks2, k0, 5)
#undef RND
#undef INJ
    uint32_t bits[8];
#pragma unroll
    for (int j = 0; j < 8; ++j) bits[j] = X0[j] ^ X1[j];

    // ---- sobel + masks ----
    float da[10], e[10];
#pragma unroll
    for (int k = 0; k < 10; ++k) {
      da[k] = R[k] - P[k];
      e[k] = P[k] + 2.0f * Q[k] + R[k];
    }
    uint32_t candmask = 0;
#pragma unroll
    for (int j = 0; j < 8; ++j) {
      float gx = e[j + 2] - e[j];
      float gy = da[j] + 2.0f * da[j + 1] + da[j + 2];
      bool vld = (gx * gx + gy * gy + 1e-8f) > 0.01f;  // sqrt(x)>0.1 <=> x>0.01
      cnt += vld ? 1 : 0;
      candmask |= ((vld && bits[j] >= BITCUT) ? 1u : 0u) << j;
    }
    if (candmask) {  // rare: ~1.2% of pixels -> ONE atomic, then free stores
      int base = atomicAdd(s_cn, __popc(candmask));
      do {
        int j = __ffs(candmask) - 1;
        candmask &= candmask - 1;
        if (base < SLICE_CAP) {
          uint32_t m = m_from_bits(bits[j]);
          stage[base] = ((unsigned long long)m << 32) | (prow + (uint32_t)j);
        }
        ++base;
      } while (candmask);
    }
#pragma unroll
    for (int k = 0; k < 10; ++k) { P[k] = Q[k]; Q[k] = R[k]; }  // rotate ring
  }
#pragma unroll
  for (int o = 32; o > 0; o >>= 1) cnt += __shfl_down(cnt, o);
  if (lane == 0) atomicAdd(s_cv, cnt);
}

__global__ __launch_bounds__(256, 4) void sobel_cand(
    const float* __restrict__ pred, const float* __restrict__ tgt,
    int2* __restrict__ g_scnt, unsigned long long* __restrict__ g_cand,
    uint32_t* __restrict__ g_hmax, int* __restrict__ g_done) {
  const int bid = blockIdx.x;
  const int b = bid >> 4, s = bid & 15;
  const int t = threadIdx.x;
  __shared__ unsigned long long stage[SLICE_CAP];
  __shared__ int s_cn, s_cv;
  if (t == 0) { s_cn = 0; s_cv = 0; }
  if (bid == 0) {  // reset K3's fused-reduction state (K3 runs 2 kernels later)
    if (t < 64) g_hmax[t] = 0u;
    if (t == 64) *g_done = 0;
  }
  __syncthreads();
  if (b < 64) sobel_body<true>(pred + (size_t)b * NPIX, b, s, t, stage, &s_cn, &s_cv);
  else        sobel_body<false>(tgt + (size_t)(b - 64) * NPIX, b, s, t, stage, &s_cn, &s_cv);
  __syncthreads();
  const int raw = s_cn;
  const int n = raw < SLICE_CAP ? raw : SLICE_CAP;
  for (int i = t; i < n; i += 256) g_cand[(size_t)bid * SLICE_CAP + i] = stage[i];
  if (t == 0) g_scnt[bid] = make_int2(s_cv, raw);
}

// ---------------- K2 resolve (1 block of 1024 per image-side) ----------------
__global__ __launch_bounds__(K2_BS) void resolve_kernel(
    const float* __restrict__ pred, const float* __restrict__ tgt,
    const int2* __restrict__ g_scnt, unsigned long long* __restrict__ g_cand,
    uint32_t* __restrict__ g_pts, int* __restrict__ g_counts) {
  const int img = blockIdx.x;
  const int t = threadIdx.x;
  const int lane = t & 63;

  __shared__ unsigned long long cand_s[16 * SLICE_CAP];  // 40 KB
  __shared__ int segc[16], segoff[17];
  __shared__ int s_scx[16], s_scy[16];
  __shared__ int s_info[4];  // cv, cnt_hi_sum, ovf, ncand_rebuilt
  __shared__ int ch[256];
  __shared__ int fh[1024];
  __shared__ int aux[256];
  __shared__ unsigned long long ties[256];
  __shared__ int s_pos, s_nt, s_T1, s_r1, s_T2, s_r2, s_n;

  if (t < 16) {
    int2 v = g_scnt[img * 16 + t];
    s_scx[t] = v.x; s_scy[t] = v.y;
    segc[t] = v.y < SLICE_CAP ? v.y : SLICE_CAP;
  }
  if (t == 0) { s_pos = 0; s_nt = 0; }
  __syncthreads();
  if (t == 0) {
    int cv = 0, hi = 0, ovf = 0, off = 0;
    for (int s = 0; s < 16; ++s) {
      cv += s_scx[s]; hi += s_scy[s];
      if (s_scy[s] > SLICE_CAP) ovf = 1;
      segoff[s] = off; off += segc[s];
    }
    segoff[16] = off;
    s_n = off;
    s_info[0] = cv; s_info[1] = hi; s_info[2] = ovf;
  }
  __syncthreads();
  const int cv = s_info[0];
  if (cv == 0) {  // center fallback
    if (t == 0) { g_pts[img * NSEL] = (256u << 16) | 256u; g_counts[img] = 1; }
    return;
  }
  const int need = cv < NSEL ? cv : NSEL;
  const bool slow = (s_info[2] != 0) || (s_info[1] < need);

  unsigned long long* C = g_cand + (size_t)img * 16 * SLICE_CAP;

  if (slow) {
    // ---- exact rebuild (statistically never taken): rescan whole image ----
    const bool isPred = img < 64;
    const float* im = isPred ? pred + (size_t)img * NPIX : tgt + (size_t)(img - 64) * NPIX;
    uint32_t k0, k1;
    tf2x32(0u, 1u, 0u, (uint32_t)img, k0, k1);
    if (t < 256) ch[t] = 0;
    __syncthreads();
    for (int p = t; p < NPIX; p += K2_BS) {
      int r = p >> 9, c = p & 511;
      float gx = (ldval(im, r - 1, c + 1, isPred) - ldval(im, r - 1, c - 1, isPred)) +
                 2.0f * (ldval(im, r, c + 1, isPred) - ldval(im, r, c - 1, isPred)) +
                 (ldval(im, r + 1, c + 1, isPred) - ldval(im, r + 1, c - 1, isPred));
      float gy = (ldval(im, r + 1, c - 1, isPred) - ldval(im, r - 1, c - 1, isPred)) +
                 2.0f * (ldval(im, r + 1, c, isPred) - ldval(im, r - 1, c, isPred)) +
                 (ldval(im, r + 1, c + 1, isPred) - ldval(im, r - 1, c + 1, isPred));
      if ((gx * gx + gy * gy + 1e-8f) > 0.01f) {
        uint32_t m = pixel_m(k0, k1, p);
        uint32_t cb = m >> 14; if (cb > 255u) cb = 255u;
        atomicAdd(&ch[cb], 1);
      }
    }
    __syncthreads();
    if (t < 256) aux[t] = ch[t];
    __syncthreads();
    for (int o = 1; o < 256; o <<= 1) {
      int v = 0;
      if (t < 256 && t + o < 256) v = aux[t + o];
      __syncthreads();
      if (t < 256) aux[t] += v;
      __syncthreads();
    }
    if (t < 256) {
      int nx = (t + 1 < 256) ? aux[t + 1] : 0;
      if (aux[t] >= need && nx < need) s_T1 = t;
    }
    __syncthreads();
    const uint32_t Tc = (uint32_t)s_T1;
    if (t == 0) s_info[3] = 0;
    __syncthreads();
    for (int p = t; p < NPIX; p += K2_BS) {
      int r = p >> 9, c = p & 511;
      float gx = (ldval(im, r - 1, c + 1, isPred) - ldval(im, r - 1, c - 1, isPred)) +
                 2.0f * (ldval(im, r, c + 1, isPred) - ldval(im, r, c - 1, isPred)) +
                 (ldval(im, r + 1, c + 1, isPred) - ldval(im, r + 1, c - 1, isPred));
      float gy = (ldval(im, r + 1, c - 1, isPred) - ldval(im, r - 1, c - 1, isPred)) +
                 2.0f * (ldval(im, r + 1, c, isPred) - ldval(im, r - 1, c, isPred)) +
                 (ldval(im, r + 1, c + 1, isPred) - ldval(im, r - 1, c + 1, isPred));
      if ((gx * gx + gy * gy + 1e-8f) > 0.01f) {
        uint32_t m = pixel_m(k0, k1, p);
        uint32_t cb = m >> 14; if (cb > 255u) cb = 255u;
        if (cb >= Tc) {
          int i = atomicAdd(&s_info[3], 1);
          if (i < 16 * SLICE_CAP) C[i] = ((unsigned long long)m << 32) | (uint32_t)p;
        }
      }
    }
    __syncthreads();
    if (t == 0) s_n = s_info[3] < 16 * SLICE_CAP ? s_info[3] : 16 * SLICE_CAP;
    __syncthreads();
  }

  // ---- stage candidates into LDS (atomic-free segmented compaction) ----
  {
    const int nn = s_n;
    if (slow) {
      for (int i = t; i < nn; i += K2_BS) cand_s[i] = C[i];
    } else {
      for (int i = t; i < 16 * SLICE_CAP; i += K2_BS) {
        int s = i / SLICE_CAP;
        int o = i - s * SLICE_CAP;
        if (o < segc[s]) cand_s[segoff[s] + o] = C[i];
      }
    }
  }
  if (t < 256) ch[t] = 0;
  fh[t] = 0;  // blockDim == 1024 covers all bins
  __syncthreads();
  const int n = s_n;

  // ---- coarse histogram ----
  if (!slow) {
    // BITCUT-filtered candidates have cb in {253,254,255}: local counters +
    // wave reduce -> 3 atomics/wave (was ~3K same-address LDS atomics).
    int l0 = 0, l1 = 0, l2 = 0;
    for (int i = t; i < n; i += K2_BS) {
      uint32_t cb = (uint32_t)(cand_s[i] >> 32) >> 14; if (cb > 255u) cb = 255u;
      if (cb == 253u) ++l0; else if (cb == 254u) ++l1; else ++l2;
    }
#pragma unroll
    for (int o = 32; o > 0; o >>= 1) {
      l0 += __shfl_down(l0, o); l1 += __shfl_down(l1, o); l2 += __shfl_down(l2, o);
    }
    if (lane == 0) {
      if (l0) atomicAdd(&ch[253], l0);
      if (l1) atomicAdd(&ch[254], l1);
      if (l2) atomicAdd(&ch[255], l2);
    }
  } else {
    for (int i = t; i < n; i += K2_BS) {
      uint32_t cb = (uint32_t)(cand_s[i] >> 32) >> 14; if (cb > 255u) cb = 255u;
      atomicAdd(&ch[cb], 1);
    }
  }
  __syncthreads();
  // 256-wide suffix scan (threads 0..255; barriers unconditional)
  if (t < 256) aux[t] = ch[t];
  __syncthreads();
  for (int o = 1; o < 256; o <<= 1) {
    int v = 0;
    if (t < 256 && t + o < 256) v = aux[t + o];
    __syncthreads();
    if (t < 256) aux[t] += v;
    __syncthreads();
  }
  if (t < 256) {
    int nx = (t + 1 < 256) ? aux[t + 1] : 0;
    if (aux[t] >= need && nx < need) { s_T1 = t; s_r1 = need - nx; }
  }
  __syncthreads();
  const uint32_t T1 = (uint32_t)s_T1;
  const int r1 = s_r1;
  const uint32_t baseM = T1 << 14;

  // ---- pass 2: emit cb>T1 (ballot-aggregated), fine-hist cb==T1 ----
  for (int base = 0; base < n; base += K2_BS) {
    const int i = base + t;
    const bool in = i < n;
    unsigned long long e = in ? cand_s[i] : 0ull;
    uint32_t m = (uint32_t)(e >> 32), p = (uint32_t)e;
    uint32_t cb = m >> 14; if (cb > 255u) cb = 255u;
    bool emit = in && cb > T1;
    unsigned long long msk = __ballot(emit);
    if (msk) {
      int leader = __ffsll(msk) - 1;
      int bpos = 0;
      if (lane == leader) bpos = atomicAdd(&s_pos, __popcll(msk));
      bpos = __shfl(bpos, leader);
      if (emit)
        g_pts[img * NSEL + bpos + __popcll(msk & ((1ull << lane) - 1ull))] = pack_pt(p);
    }
    if (in && cb == T1) {
      uint32_t f = (m - baseM) >> 4; if (f > 1023u) f = 1023u;
      atomicAdd(&fh[f], 1);
    }
  }
  __syncthreads();
  // 1024-wide suffix scan over fh (thread t owns bin t)
  for (int o = 1; o < 1024; o <<= 1) {
    int v = (t + o < 1024) ? fh[t + o] : 0;
    __syncthreads();
    fh[t] += v;
    __syncthreads();
  }
  {
    int nx = (t < 1023) ? fh[t + 1] : 0;
    if (fh[t] >= r1 && nx < r1) { s_T2 = t; s_r2 = r1 - nx; }
  }
  __syncthreads();
  const int T2 = s_T2, r2 = s_r2;

  // ---- pass 3: emit f>T2 (ballot-aggregated), collect ties f==T2 ----
  for (int base = 0; base < n; base += K2_BS) {
    const int i = base + t;
    const bool in = i < n;
    unsigned long long e = in ? cand_s[i] : 0ull;
    uint32_t m = (uint32_t)(e >> 32), p = (uint32_t)e;
    uint32_t cb = m >> 14; if (cb > 255u) cb = 255u;
    uint32_t f = (m - baseM) >> 4; if (f > 1023u) f = 1023u;
    const bool isT1 = in && cb == T1;
    bool emit = isT1 && (int)f > T2;
    bool tie  = isT1 && (int)f == T2;
    unsigned long long msk = __ballot(emit);
    if (msk) {
      int leader = __ffsll(msk) - 1;
      int bpos = 0;
      if (lane == leader) bpos = atomicAdd(&s_pos, __popcll(msk));
      bpos = __shfl(bpos, leader);
      if (emit)
        g_pts[img * NSEL + bpos + __popcll(msk & ((1ull << lane) - 1ull))] = pack_pt(p);
    }
    unsigned long long mt = __ballot(tie);
    if (mt) {
      int leader = __ffsll(mt) - 1;
      int bpos = 0;
      if (lane == leader) bpos = atomicAdd(&s_nt, __popcll(mt));
      bpos = __shfl(bpos, leader);
      int idx = bpos + __popcll(mt & ((1ull << lane) - 1ull));
      if (tie && idx < 256) ties[idx] = e;
    }
  }
  __syncthreads();
  const int nt = s_nt < 256 ? s_nt : 256;
  for (int i = t; i < nt; i += K2_BS) {
    unsigned long long e = ties[i];
    uint32_t mi = (uint32_t)(e >> 32), pi = (uint32_t)e;
    int rank = 0;
    for (int j = 0; j < nt; ++j) {
      unsigned long long e2 = ties[j];
      uint32_t mj = (uint32_t)(e2 >> 32), pj = (uint32_t)e2;
      rank += (mj > mi) || (mj == mi && pj < pi);
    }
    if (rank < r2) {
      int pos = atomicAdd(&s_pos, 1);
      g_pts[img * NSEL + pos] = pack_pt(pi);
    }
  }
  __syncthreads();
  if (t == 0) g_counts[img] = s_pos;  // == need
}

// ---------------- K3 (absorbs K4 via ticket finisher) ----------------
__global__ __launch_bounds__(256) void haus_kernel(
    const uint32_t* __restrict__ g_pts, const int* __restrict__ g_counts,
    uint32_t* __restrict__ g_hmax, int* __restrict__ g_done,
    float* __restrict__ out) {
  const int bid = blockIdx.x;
  const int img = bid >> 3;
  const int dir = (bid >> 2) & 1;
  const int seg = bid & 3;
  const int t = threadIdx.x;
  const int iOwn = dir ? 64 + img : img;
  const int iOth = dir ? img : 64 + img;
  const int nOwn = g_counts[iOwn];
  const int nOth = g_counts[iOth];
  __shared__ __align__(16) float2 o[NSEL];
  __shared__ float red[256];
  __shared__ int s_ticket;
  for (int i = t; i < nOth; i += 256) {
    uint32_t v = g_pts[iOth * NSEL + i];
    o[i] = make_float2((float)(v >> 16), (float)(v & 0xFFFFu));
  }
  __syncthreads();
  const float4* o4 = (const float4*)o;  // 2 points per LDS read
  float best = 0.0f;
  const int lo = seg * 250;
  const int hi = min(nOwn, lo + 250);
  for (int i = lo + t; i < hi; i += 256) {
    uint32_t v = g_pts[iOwn * NSEL + i];
    float pr = (float)(v >> 16), pc = (float)(v & 0xFFFFu);
    // 4 independent accumulators: break the serial fmin dependency chain
    float mn0 = 3.4e38f, mn1 = 3.4e38f, mn2 = 3.4e38f, mn3 = 3.4e38f;
    int j = 0;
    for (; j + 3 < nOth; j += 4) {
      float4 A = o4[j >> 1];        // pts j, j+1
      float4 B = o4[(j >> 1) + 1];  // pts j+2, j+3
      float dr0 = pr - A.x, dc0 = pc - A.y;
      float dr1 = pr - A.z, dc1 = pc - A.w;
      float dr2 = pr - B.x, dc2 = pc - B.y;
      float dr3 = pr - B.z, dc3 = pc - B.w;
      mn0 = fminf(mn0, dr0 * dr0 + dc0 * dc0);
      mn1 = fminf(mn1, dr1 * dr1 + dc1 * dc1);
      mn2 = fminf(mn2, dr2 * dr2 + dc2 * dc2);
      mn3 = fminf(mn3, dr3 * dr3 + dc3 * dc3);
    }
    for (; j < nOth; ++j) {
      float dr = pr - o[j].x, dc = pc - o[j].y;
      mn0 = fminf(mn0, dr * dr + dc * dc);
    }
    float mn = fminf(fminf(mn0, mn1), fminf(mn2, mn3));
    best = fmaxf(best, mn);
  }
  red[t] = best;
  __syncthreads();
  for (int st = 128; st > 0; st >>= 1) {
    if (t < st) red[t] = fmaxf(red[t], red[t + st]);
    __syncthreads();
  }
  // fused K4: per-img atomic max (d2 >= 0 so uint order == float order),
  // then the 512th block to arrive computes the final mean.
  if (t == 0) {
    atomicMax(&g_hmax[img], __float_as_uint(red[0]));
    __threadfence();
    s_ticket = atomicAdd(g_done, 1);
  }
  __syncthreads();
  if (s_ticket == 511) {
    __threadfence();
    if (t < 64) {  // wave 0: lane t owns image t (same order as old fin_kernel)
      uint32_t u = atomicMax(&g_hmax[t], 0u);  // device-scope atomic read
      float diag = sqrtf((float)(HH * HH + WW * WW));
      float hd = sqrtf(fmaxf(__uint_as_float(u), 0.0f)) / diag;
      hd = fminf(fmaxf(hd, 0.0f), 0.1f);
      float s = hd;
      for (int o2 = 32; o2 > 0; o2 >>= 1) s += __shfl_down(s, o2);
      if (t == 0) out[0] = s * 0.015625f;
    }
  }
}

// ---------------- workspace layout (bytes) — nothing pre-zeroed ----------
#define WS_SCNT   0u                          // 2048*8 = 16384
#define WS_COUNTS 16384u                      // 512
#define WS_HMAX   (WS_COUNTS + 512u)          // 64*4 = 256 (zeroed by K1 blk0)
#define WS_DONE   (WS_HMAX + 256u)            // 4    (zeroed by K1 blk0)
#define WS_PTS    (WS_HMAX + 2048u)           // 512000
#define WS_CAND   (WS_PTS + 512000u)          // 2048*320*8 = 5242880  (~5.8 MB)

extern "C" void kernel_launch(void* const* d_in, const int* in_sizes, int n_in,
                              void* d_out, int out_size, void* d_ws, size_t ws_size,
                              hipStream_t stream) {
  const float* pred = (const float*)d_in[0];
  const float* tgt = (const float*)d_in[1];
  float* out = (float*)d_out;
  char* ws = (char*)d_ws;
  int2* g_scnt = (int2*)(ws + WS_SCNT);
  int* g_counts = (int*)(ws + WS_COUNTS);
  uint32_t* g_hmax = (uint32_t*)(ws + WS_HMAX);
  int* g_done = (int*)(ws + WS_DONE);
  uint32_t* g_pts = (uint32_t*)(ws + WS_PTS);
  unsigned long long* g_cand = (unsigned long long*)(ws + WS_CAND);

  sobel_cand<<<2048, 256, 0, stream>>>(pred, tgt, g_scnt, g_cand, g_hmax, g_done);
  resolve_kernel<<<128, K2_BS, 0, stream>>>(pred, tgt, g_scnt, g_cand, g_pts, g_counts);
  haus_kernel<<<512, 256, 0, stream>>>(g_pts, g_counts, g_hmax, g_done, out);
}